// Round 15
// baseline (69.388 us; speedup 1.0000x reference)
//
#include <hip/hip_runtime.h>
#include <math.h>
#include <stdint.h>

#define NB1    4096
#define NBTOT  8192
#define NFD    128
#define NSLICE 16                // column slices
#define ECOLS  512               // columns per block
#define BROWS  128
#define BCOLS  64
#define NTILES (ECOLS / BCOLS)   // 8
#define NSL    8                 // partial slices per class

typedef __attribute__((ext_vector_type(8))) _Float16 f16x8;
typedef __attribute__((ext_vector_type(4))) float f32x4;
typedef _Float16 f16;

// async 16B global->LDS; lds base wave-uniform, HW adds lane*16
__device__ __forceinline__ void gl16(const f16* g, char* l) {
    __builtin_amdgcn_global_load_lds(
        (const __attribute__((address_space(1))) unsigned int*)g,
        (__attribute__((address_space(3))) unsigned int*)l,
        16, 0, 0);
}

// ---------------------------------------------------------------------------
// Kernel 1: row L2-normalize -> fp16 (validated R8: loss err ~0.015 << 0.0925)
// ---------------------------------------------------------------------------
__global__ void norm_k(const float* __restrict__ f1, const float* __restrict__ f2,
                       f16* __restrict__ nfh) {
    const int w = threadIdx.x >> 6, lane = threadIdx.x & 63;
    const int row = blockIdx.x * 4 + w;
    const float* src = (row < NB1) ? (f1 + (size_t)row * NFD)
                                   : (f2 + (size_t)(row - NB1) * NFD);
    const float2 v = *reinterpret_cast<const float2*>(src + 2 * lane);
    float s = v.x * v.x + v.y * v.y;
#pragma unroll
    for (int m = 32; m >= 1; m >>= 1) s += __shfl_xor(s, m, 64);
    const float inv = 1.0f / fmaxf(sqrtf(s), 1e-12f);
    const f16 h0 = (f16)(v.x * inv);
    const f16 h1 = (f16)(v.y * inv);
    const unsigned pack = (unsigned)__builtin_bit_cast(unsigned short, h0) |
                          ((unsigned)__builtin_bit_cast(unsigned short, h1) << 16);
    ((unsigned*)(nfh + (size_t)row * NFD))[lane] = pack;
}

// ---------------------------------------------------------------------------
// Kernel 2: fp16 MFMA sim-stats (R8 structure, proven 40.4us/absmax 0.0).
// Grid (16 col-slices, 64 row-tiles) = 1024 blocks = exactly 4/CU.
// 256 thr = 4 waves, 2x2 wave grid: wave w -> rows 64*(w>>1) (fa=4), cols
// 32*(w&1) (fb=2) -> 0.25 ds_read per MFMA (LDS pipe < MFMA pipe).
// ONLY change vs R8: __launch_bounds__(256,4) -> 16 waves/CU (was 3).
// VGPR evidence: R9 measured 84 VGPR (+32 AGPR acc) for this shape -> fits.
// A-frags register-resident (64 VGPR, tile-invariant). LDS = B dbuf 2x16KB.
// 4-bit XOR swizzle via pre-swizzled global_load_lds source (0 conflicts).
// ---------------------------------------------------------------------------
__global__ __launch_bounds__(256, 4) void simstat_mfma(const f16* __restrict__ nfh,
                                                       float* __restrict__ posp,
                                                       float* __restrict__ sexpp) {
    extern __shared__ __align__(16) char smem[];   // 32768 = 2 x 16KB

    const int e    = blockIdx.x;          // column slice 0..15
    const int rt   = blockIdx.y;
    const int row0 = rt * BROWS;
    const int col0e = e * ECOLS;
    const bool same = ((row0 >= NB1) == (e >= 8));
    const int p = e & 7;

    const int t    = threadIdx.x;
    const int w    = t >> 6;
    const int lane = t & 63;
    const int lr   = lane & 15;
    const int lg   = lane >> 4;
    const int rowbase = 64 * (w >> 1);    // 2 row-stripes of 64
    const int colbase = 32 * (w & 1);     // 2 col-stripes of 32

    // ---- stage mapping (loop-invariant): 4 waves x 4KB = 16KB tile ----
    int goffs[4], dbase[4];
#pragma unroll
    for (int i = 0; i < 4; ++i) {
        const int base = w * 4096 + i * 1024;
        const int d    = base + lane * 16;
        const int sr   = d >> 8;            // dest row 0..63
        const int slot = (d >> 4) & 15;
        const int kc   = slot ^ (sr & 15);  // source k-chunk (involution)
        goffs[i] = sr * NFD + kc * 8;
        dbase[i] = base;
    }
    // read offsets (row&15 == lr since colbase,16*fb are multiples of 16)
    int rbo[2], koff[4];
#pragma unroll
    for (int fb = 0; fb < 2; ++fb) rbo[fb] = (colbase + 16 * fb + lr) * 256;
#pragma unroll
    for (int ks = 0; ks < 4; ++ks) koff[ks] = (((ks << 2) + lg) ^ lr) << 4;

    // ---- stage B tile 0 (async) ----
    {
        const f16* g0 = nfh + (size_t)col0e * NFD;
#pragma unroll
        for (int i = 0; i < 4; ++i) gl16(g0 + goffs[i], smem + dbase[i]);
    }

    // ---- A fragments -> registers (tile-invariant): 16 x 4 VGPR ----
    f16x8 ah[4][4];
#pragma unroll
    for (int ks = 0; ks < 4; ++ks)
#pragma unroll
        for (int fa = 0; fa < 4; ++fa) {
            const size_t off = (size_t)(row0 + rowbase + 16 * fa + lr) * NFD + 32 * ks + 8 * lg;
            ah[ks][fa] = *reinterpret_cast<const f16x8*>(nfh + off);
        }

    __syncthreads();   // tile0 + A loads complete

    float stat[4][4];
#pragma unroll
    for (int fa = 0; fa < 4; ++fa)
#pragma unroll
        for (int r = 0; r < 4; ++r) stat[fa][r] = same ? -3.0e38f : 0.0f;
    const float K2 = 1.44269504089f / 0.07f;   // log2(e)/tau
    const float invtau = 1.0f / 0.07f;

#pragma unroll 1
    for (int tile = 0; tile < NTILES; ++tile) {
        const char* bufB = smem + (tile & 1) * 16384;

        // issue next-tile stage early (lands during compute, drained at barrier)
        if (tile + 1 < NTILES) {
            char* nb = smem + ((tile + 1) & 1) * 16384;
            const f16* gn = nfh + (size_t)(col0e + (tile + 1) * BCOLS) * NFD;
#pragma unroll
            for (int i = 0; i < 4; ++i) gl16(gn + goffs[i], nb + dbase[i]);
        }

        f32x4 acc[4][2];
#pragma unroll
        for (int fa = 0; fa < 4; ++fa)
#pragma unroll
            for (int fb = 0; fb < 2; ++fb) {
                f32x4 z = {0.0f, 0.0f, 0.0f, 0.0f};
                acc[fa][fb] = z;
            }

#pragma unroll
        for (int ks = 0; ks < 4; ++ks) {
            f16x8 b[2];
#pragma unroll
            for (int fb = 0; fb < 2; ++fb)
                b[fb] = *(const f16x8*)(bufB + rbo[fb] + koff[ks]);
            __builtin_amdgcn_s_setprio(1);
#pragma unroll
            for (int fb = 0; fb < 2; ++fb)
#pragma unroll
                for (int fa = 0; fa < 4; ++fa)
                    acc[fa][fb] = __builtin_amdgcn_mfma_f32_16x16x32_f16(ah[ks][fa], b[fb], acc[fa][fb], 0, 0, 0);
            __builtin_amdgcn_s_setprio(0);
        }

        // fold acc into stat; C/D: col=lane&15, row=4*lg+reg (m89-verified)
        if (same) {
            const int col0 = col0e + tile * BCOLS;
#pragma unroll
            for (int fa = 0; fa < 4; ++fa)
#pragma unroll
                for (int fb = 0; fb < 2; ++fb)
#pragma unroll
                    for (int r = 0; r < 4; ++r) {
                        const int grow = row0 + rowbase + 16 * fa + 4 * lg + r;
                        const int gcol = col0 + colbase + 16 * fb + lr;
                        stat[fa][r] = (grow == gcol) ? stat[fa][r]
                                                     : fmaxf(stat[fa][r], acc[fa][fb][r]);
                    }
        } else {
#pragma unroll
            for (int fa = 0; fa < 4; ++fa)
#pragma unroll
                for (int fb = 0; fb < 2; ++fb)
#pragma unroll
                    for (int r = 0; r < 4; ++r)
                        stat[fa][r] += exp2f(acc[fa][fb][r] * K2);
        }

        __syncthreads();
    }

    // reduce over the 16 cols held across lr (lane bits 0..3)
#pragma unroll
    for (int m = 1; m <= 8; m <<= 1) {
#pragma unroll
        for (int fa = 0; fa < 4; ++fa)
#pragma unroll
            for (int r = 0; r < 4; ++r) {
                const float o = __shfl_xor(stat[fa][r], m, 64);
                stat[fa][r] = same ? fmaxf(stat[fa][r], o) : (stat[fa][r] + o);
            }
    }

    // combine the two col-stripe waves per row via LDS scratch
    float* scratch = (float*)smem;
    if (lr == 0) {
#pragma unroll
        for (int fa = 0; fa < 4; ++fa)
#pragma unroll
            for (int r = 0; r < 4; ++r) {
                const int rl = rowbase + 16 * fa + 4 * lg + r;
                scratch[(w & 1) * 128 + rl] = stat[fa][r];
            }
    }
    __syncthreads();
    if (t < 128) {
        const float v0 = scratch[t];
        const float v1 = scratch[128 + t];
        const float v = same ? fmaxf(v0, v1) * invtau : (v0 + v1);
        (same ? posp : sexpp)[(size_t)p * NBTOT + row0 + t] = v;
    }
}

// ---------------------------------------------------------------------------
// Kernel 3a: per-row loss partials, 32 blocks. loss_i = log1p(S*exp(-pos))
// ---------------------------------------------------------------------------
__global__ void loss_part(const float* __restrict__ posp, const float* __restrict__ sexpp,
                          float* __restrict__ partial) {
    const int i = blockIdx.x * 256 + threadIdx.x;
    float pv = -3.0e38f, se = 0.0f;
#pragma unroll
    for (int s = 0; s < NSL; ++s) {
        pv = fmaxf(pv, posp[(size_t)s * NBTOT + i]);
        se += sexpp[(size_t)s * NBTOT + i];
    }
    float l = log1pf(se * __expf(-pv));
#pragma unroll
    for (int m = 32; m >= 1; m >>= 1) l += __shfl_xor(l, m, 64);
    __shared__ float part[4];
    if ((threadIdx.x & 63) == 0) part[threadIdx.x >> 6] = l;
    __syncthreads();
    if (threadIdx.x == 0)
        partial[blockIdx.x] = part[0] + part[1] + part[2] + part[3];
}

// Kernel 3b: final combine (1 wave).
__global__ void loss_final(const float* __restrict__ partial, float* __restrict__ out) {
    const int t = threadIdx.x;
    float s = (t < 32) ? partial[t] : 0.0f;
#pragma unroll
    for (int m = 32; m >= 1; m >>= 1) s += __shfl_xor(s, m, 64);
    if (t == 0) out[0] = s / (float)NBTOT;
}

// ---------------------------------------------------------------------------
extern "C" void kernel_launch(void* const* d_in, const int* in_sizes, int n_in,
                              void* d_out, int out_size, void* d_ws, size_t ws_size,
                              hipStream_t stream) {
    const float* f1 = (const float*)d_in[0];
    const float* f2 = (const float*)d_in[1];

    f16*   nfh     = (f16*)d_ws;                          // 2 MB
    float* posp    = (float*)(nfh + (size_t)NBTOT * NFD); // 8*8192 f32
    float* sexpp   = posp + (size_t)NSL * NBTOT;          // 8*8192 f32
    float* partial = sexpp + (size_t)NSL * NBTOT;         // 32 f32

    (void)hipFuncSetAttribute(reinterpret_cast<const void*>(simstat_mfma),
                              hipFuncAttributeMaxDynamicSharedMemorySize, 32768);

    norm_k<<<NBTOT / 4, 256, 0, stream>>>(f1, f2, nfh);
    simstat_mfma<<<dim3(NSLICE, 64), 256, 32768, stream>>>(nfh, posp, sexpp);
    loss_part<<<NBTOT / 256, 256, 0, stream>>>(posp, sexpp, partial);
    loss_final<<<1, 64, 0, stream>>>(partial, (float*)d_out);
}

// Round 16
// 47.125 us; speedup vs baseline: 1.4724x; 1.4724x over previous
//
#include <hip/hip_runtime.h>
#include <math.h>
#include <stdint.h>

#define NB1    4096
#define NBTOT  8192
#define NFD    128
#define NSLICE 16                // column slices
#define ECOLS  512               // columns per block
#define BROWS  128
#define BCOLS  64
#define NTILES (ECOLS / BCOLS)   // 8
#define NSL    8                 // partial slices per class

typedef __attribute__((ext_vector_type(8))) _Float16 f16x8;
typedef __attribute__((ext_vector_type(4))) float f32x4;
typedef _Float16 f16;

// async 16B global->LDS; lds base wave-uniform, HW adds lane*16
__device__ __forceinline__ void gl16(const f16* g, char* l) {
    __builtin_amdgcn_global_load_lds(
        (const __attribute__((address_space(1))) unsigned int*)g,
        (__attribute__((address_space(3))) unsigned int*)l,
        16, 0, 0);
}

// ---------------------------------------------------------------------------
// Kernel 1: row L2-normalize -> fp16 (validated R8: loss err ~0.015 << 0.0925)
// ---------------------------------------------------------------------------
__global__ void norm_k(const float* __restrict__ f1, const float* __restrict__ f2,
                       f16* __restrict__ nfh) {
    const int w = threadIdx.x >> 6, lane = threadIdx.x & 63;
    const int row = blockIdx.x * 4 + w;
    const float* src = (row < NB1) ? (f1 + (size_t)row * NFD)
                                   : (f2 + (size_t)(row - NB1) * NFD);
    const float2 v = *reinterpret_cast<const float2*>(src + 2 * lane);
    float s = v.x * v.x + v.y * v.y;
#pragma unroll
    for (int m = 32; m >= 1; m >>= 1) s += __shfl_xor(s, m, 64);
    const float inv = 1.0f / fmaxf(sqrtf(s), 1e-12f);
    const f16 h0 = (f16)(v.x * inv);
    const f16 h1 = (f16)(v.y * inv);
    const unsigned pack = (unsigned)__builtin_bit_cast(unsigned short, h0) |
                          ((unsigned)__builtin_bit_cast(unsigned short, h1) << 16);
    ((unsigned*)(nfh + (size_t)row * NFD))[lane] = pack;
}

// ---------------------------------------------------------------------------
// Kernel 2: R8 geometry (proven 40.4us) + T4 counted-vmcnt pipeline.
// Grid (16 slices, 64 row-tiles) = 1024 blocks. 256 thr = 4 waves, 2x2 grid:
// wave w -> rows 64*(w>>1) (fa=4), cols 32*(w&1) (fb=2). A-frags in regs.
// LDS: 3 x 16KB rotating B buffers (2 tiles of prefetch IN FLIGHT across
// barriers). Per tile: vmcnt(4) [my tile-t loads done, t+1/t+2 in flight]
// -> raw s_barrier [publish] -> issue stage(t+2) -> compute. NO vmcnt(0)
// drain in the loop (T4/m218). launch_bounds (256,3): proven 84-VGPR alloc.
// ---------------------------------------------------------------------------
__global__ __launch_bounds__(256, 3) void simstat_mfma(const f16* __restrict__ nfh,
                                                       float* __restrict__ posp,
                                                       float* __restrict__ sexpp) {
    __shared__ __align__(16) char smem[49152];   // 3 x 16KB

    const int e    = blockIdx.x;          // column slice 0..15
    const int rt   = blockIdx.y;
    const int row0 = rt * BROWS;
    const int col0e = e * ECOLS;
    const bool same = ((row0 >= NB1) == (e >= 8));
    const int p = e & 7;

    const int t    = threadIdx.x;
    const int w    = t >> 6;
    const int lane = t & 63;
    const int lr   = lane & 15;
    const int lg   = lane >> 4;
    const int rowbase = 64 * (w >> 1);    // 2 row-stripes of 64
    const int colbase = 32 * (w & 1);     // 2 col-stripes of 32

    // ---- stage mapping (loop-invariant): 4 waves x 4KB = 16KB tile ----
    int goffs[4], dbase[4];
#pragma unroll
    for (int i = 0; i < 4; ++i) {
        const int base = w * 4096 + i * 1024;
        const int d    = base + lane * 16;
        const int sr   = d >> 8;            // dest row 0..63
        const int slot = (d >> 4) & 15;
        const int kc   = slot ^ (sr & 15);  // source k-chunk (involution)
        goffs[i] = sr * NFD + kc * 8;
        dbase[i] = base;
    }
    int rbo[2], koff[4];
#pragma unroll
    for (int fb = 0; fb < 2; ++fb) rbo[fb] = (colbase + 16 * fb + lr) * 256;
#pragma unroll
    for (int ks = 0; ks < 4; ++ks) koff[ks] = (((ks << 2) + lg) ^ lr) << 4;

    // ---- A fragments first (so vmcnt(4) in loop covers them) ----
    f16x8 ah[4][4];
#pragma unroll
    for (int ks = 0; ks < 4; ++ks)
#pragma unroll
        for (int fa = 0; fa < 4; ++fa) {
            const size_t off = (size_t)(row0 + rowbase + 16 * fa + lr) * NFD + 32 * ks + 8 * lg;
            ah[ks][fa] = *reinterpret_cast<const f16x8*>(nfh + off);
        }

    // ---- stage tiles 0,1 into buf0,buf1 ----
#pragma unroll
    for (int i = 0; i < 4; ++i) gl16(nfh + (size_t)col0e * NFD + goffs[i], smem + dbase[i]);
#pragma unroll
    for (int i = 0; i < 4; ++i) gl16(nfh + (size_t)(col0e + BCOLS) * NFD + goffs[i], smem + 16384 + dbase[i]);

    float stat[4][4];
#pragma unroll
    for (int fa = 0; fa < 4; ++fa)
#pragma unroll
        for (int r = 0; r < 4; ++r) stat[fa][r] = same ? -3.0e38f : 0.0f;
    const float K2 = 1.44269504089f / 0.07f;   // log2(e)/tau
    const float invtau = 1.0f / 0.07f;

#define COMPUTE(TILE_, BUF_)                                                  \
    {                                                                         \
        const char* bufB = smem + (BUF_) * 16384;                             \
        f32x4 acc[4][2];                                                      \
        _Pragma("unroll")                                                     \
        for (int fa = 0; fa < 4; ++fa)                                        \
            _Pragma("unroll")                                                 \
            for (int fb = 0; fb < 2; ++fb) {                                  \
                f32x4 z = {0.0f, 0.0f, 0.0f, 0.0f};                           \
                acc[fa][fb] = z;                                              \
            }                                                                 \
        _Pragma("unroll")                                                     \
        for (int ks = 0; ks < 4; ++ks) {                                      \
            f16x8 b[2];                                                       \
            _Pragma("unroll")                                                 \
            for (int fb = 0; fb < 2; ++fb)                                    \
                b[fb] = *(const f16x8*)(bufB + rbo[fb] + koff[ks]);           \
            __builtin_amdgcn_s_setprio(1);                                    \
            _Pragma("unroll")                                                 \
            for (int fb = 0; fb < 2; ++fb)                                    \
                _Pragma("unroll")                                             \
                for (int fa = 0; fa < 4; ++fa)                                \
                    acc[fa][fb] = __builtin_amdgcn_mfma_f32_16x16x32_f16(ah[ks][fa], b[fb], acc[fa][fb], 0, 0, 0); \
            __builtin_amdgcn_s_setprio(0);                                    \
        }                                                                     \
        if (same) {                                                           \
            const int col0 = col0e + (TILE_) * BCOLS;                         \
            _Pragma("unroll")                                                 \
            for (int fa = 0; fa < 4; ++fa)                                    \
                _Pragma("unroll")                                             \
                for (int fb = 0; fb < 2; ++fb)                                \
                    _Pragma("unroll")                                         \
                    for (int r = 0; r < 4; ++r) {                             \
                        const int grow = row0 + rowbase + 16 * fa + 4 * lg + r; \
                        const int gcol = col0 + colbase + 16 * fb + lr;       \
                        stat[fa][r] = (grow == gcol) ? stat[fa][r]            \
                                                     : fmaxf(stat[fa][r], acc[fa][fb][r]); \
                    }                                                         \
        } else {                                                              \
            _Pragma("unroll")                                                 \
            for (int fa = 0; fa < 4; ++fa)                                    \
                _Pragma("unroll")                                             \
                for (int fb = 0; fb < 2; ++fb)                                \
                    _Pragma("unroll")                                         \
                    for (int r = 0; r < 4; ++r)                               \
                        stat[fa][r] += exp2f(acc[fa][fb][r] * K2);            \
        }                                                                     \
    }

    int cur = 0;   // buffer index of current tile
#pragma unroll 1
    for (int tile = 0; tile < NTILES - 1; ++tile) {
        // my tile-`tile` loads retired (t+1 still in flight = newest 4)
        asm volatile("s_waitcnt vmcnt(4)" ::: "memory");
        // publish tile data to all waves; all waves done reading the buffer
        // that stage(tile+2) will overwrite
        __builtin_amdgcn_s_barrier();
        if (tile + 2 < NTILES) {
            const int stg = (cur >= 1) ? cur - 1 : cur + 2;   // (cur+2)%3
            char* nb = smem + stg * 16384;
            const f16* gn = nfh + (size_t)(col0e + (tile + 2) * BCOLS) * NFD;
#pragma unroll
            for (int i = 0; i < 4; ++i) gl16(gn + goffs[i], nb + dbase[i]);
        }
        __builtin_amdgcn_sched_barrier(0);
        COMPUTE(tile, cur);
        cur = (cur == 2) ? 0 : cur + 1;
    }
    // last tile: drain fully
    asm volatile("s_waitcnt vmcnt(0)" ::: "memory");
    __builtin_amdgcn_s_barrier();
    COMPUTE(NTILES - 1, cur);
#undef COMPUTE

    // reduce over the 16 cols held across lr (lane bits 0..3)
#pragma unroll
    for (int m = 1; m <= 8; m <<= 1) {
#pragma unroll
        for (int fa = 0; fa < 4; ++fa)
#pragma unroll
            for (int r = 0; r < 4; ++r) {
                const float o = __shfl_xor(stat[fa][r], m, 64);
                stat[fa][r] = same ? fmaxf(stat[fa][r], o) : (stat[fa][r] + o);
            }
    }

    // combine the two col-stripe waves per row via LDS scratch (reuse smem)
    __syncthreads();
    float* scratch = (float*)smem;
    if (lr == 0) {
#pragma unroll
        for (int fa = 0; fa < 4; ++fa)
#pragma unroll
            for (int r = 0; r < 4; ++r) {
                const int rl = rowbase + 16 * fa + 4 * lg + r;
                scratch[(w & 1) * 128 + rl] = stat[fa][r];
            }
    }
    __syncthreads();
    if (t < 128) {
        const float v0 = scratch[t];
        const float v1 = scratch[128 + t];
        const float v = same ? fmaxf(v0, v1) * invtau : (v0 + v1);
        (same ? posp : sexpp)[(size_t)p * NBTOT + row0 + t] = v;
    }
}

// ---------------------------------------------------------------------------
// Kernel 3a: per-row loss partials, 32 blocks. loss_i = log1p(S*exp(-pos))
// ---------------------------------------------------------------------------
__global__ void loss_part(const float* __restrict__ posp, const float* __restrict__ sexpp,
                          float* __restrict__ partial) {
    const int i = blockIdx.x * 256 + threadIdx.x;
    float pv = -3.0e38f, se = 0.0f;
#pragma unroll
    for (int s = 0; s < NSL; ++s) {
        pv = fmaxf(pv, posp[(size_t)s * NBTOT + i]);
        se += sexpp[(size_t)s * NBTOT + i];
    }
    float l = log1pf(se * __expf(-pv));
#pragma unroll
    for (int m = 32; m >= 1; m >>= 1) l += __shfl_xor(l, m, 64);
    __shared__ float part[4];
    if ((threadIdx.x & 63) == 0) part[threadIdx.x >> 6] = l;
    __syncthreads();
    if (threadIdx.x == 0)
        partial[blockIdx.x] = part[0] + part[1] + part[2] + part[3];
}

// Kernel 3b: final combine (1 wave).
__global__ void loss_final(const float* __restrict__ partial, float* __restrict__ out) {
    const int t = threadIdx.x;
    float s = (t < 32) ? partial[t] : 0.0f;
#pragma unroll
    for (int m = 32; m >= 1; m >>= 1) s += __shfl_xor(s, m, 64);
    if (t == 0) out[0] = s / (float)NBTOT;
}

// ---------------------------------------------------------------------------
extern "C" void kernel_launch(void* const* d_in, const int* in_sizes, int n_in,
                              void* d_out, int out_size, void* d_ws, size_t ws_size,
                              hipStream_t stream) {
    const float* f1 = (const float*)d_in[0];
    const float* f2 = (const float*)d_in[1];

    f16*   nfh     = (f16*)d_ws;                          // 2 MB
    float* posp    = (float*)(nfh + (size_t)NBTOT * NFD); // 8*8192 f32
    float* sexpp   = posp + (size_t)NSL * NBTOT;          // 8*8192 f32
    float* partial = sexpp + (size_t)NSL * NBTOT;         // 32 f32

    norm_k<<<NBTOT / 4, 256, 0, stream>>>(f1, f2, nfh);
    simstat_mfma<<<dim3(NSLICE, 64), 256, 0, stream>>>(nfh, posp, sexpp);
    loss_part<<<NBTOT / 256, 256, 0, stream>>>(posp, sexpp, partial);
    loss_final<<<1, 64, 0, stream>>>(partial, (float*)d_out);
}